// Round 5
// baseline (46.807 us; speedup 1.0000x reference)
//
#include <hip/hip_runtime.h>

#define N_DIM 2048
#define F_DIM 64
#define RPB   32                      // rows per block
#define SLABC 64                      // fp32 columns per slab
#define NSLAB (N_DIM / SLABC)         // 32
#define SLAB_BYTES (RPB * SLABC * 4)  // 8192

typedef __attribute__((ext_vector_type(4))) float  f32x4;
typedef __attribute__((ext_vector_type(8))) short  s16x8;
typedef __attribute__((ext_vector_type(8))) __bf16 bf16x8;

typedef const __attribute__((address_space(1))) void gas_t;
typedef __attribute__((address_space(3))) void las_t;

static __device__ __forceinline__ unsigned short f2bf(float f) {
  unsigned int u = __builtin_bit_cast(unsigned int, f);
  u += 0x7fffu + ((u >> 16) & 1u);      // RNE to bf16
  return (unsigned short)(u >> 16);
}

// Prep (grid 72):
//  blocks 0..63  — MFMA B-fragments of bf16(v): lane l holds
//    B[k = 8*(l/16)+j][col = l%16], stored [kt(64)][tile(4)][lane(64)][j(8)]
//  blocks 64..71 — s_half[k] = 0.5 * sum_f v[k][f]^2
__global__ __launch_bounds__(256) void fm_prep(const float* __restrict__ v,
                                               unsigned short* __restrict__ vb,
                                               float* __restrict__ sh) {
  const int blk = blockIdx.x;
  const int tid = threadIdx.x;
  if (blk < 64) {
    const int g  = blk * 256 + tid;
    const int fl = g & 63;
    const int t  = (g >> 6) & 3;
    const int kt = g >> 8;
    const int kbase = kt * 32 + ((fl >> 4) << 3);
    const int f = t * 16 + (fl & 15);
    s16x8 a;
#pragma unroll
    for (int j = 0; j < 8; ++j)
      a[j] = (short)f2bf(v[(size_t)(kbase + j) * F_DIM + f]);
    *(s16x8*)(vb + (size_t)g * 8) = a;
  } else {
    const int k = (blk - 64) * 256 + tid;
    const f32x4* row = (const f32x4*)(v + (size_t)k * F_DIM);
    float s = 0.0f;
#pragma unroll
    for (int i = 0; i < 16; ++i) {
      f32x4 q = row[i];
      s += q[0]*q[0] + q[1]*q[1] + q[2]*q[2] + q[3]*q[3];
    }
    sh[k] = 0.5f * s;
  }
}

// Main: 512 blocks x 512 threads (8 waves). Block owns 32 rows.
// Wave w -> row-tile h=w>>2 (16 rows), F-tile t=w&3 (16 cols). x is staged
// through LDS slabs (32 rows x 64 cols) via global_load_lds with XOR-swizzled
// source; per-slab double buffer + one barrier. lin computed by waves t<2.
__global__ __launch_bounds__(512, 4) void fm_main(const float* __restrict__ x,
                                                  const float* __restrict__ w0,
                                                  const float* __restrict__ w1,
                                                  const unsigned short* __restrict__ vb,
                                                  const float* __restrict__ sh,
                                                  float* __restrict__ out) {
  const int tid  = threadIdx.x;
  const int lane = tid & 63;
  const int w    = tid >> 6;            // 0..7
  const int h    = w >> 2;              // row-tile 0/1
  const int t    = w & 3;               // F-tile 0..3
  const int rowbase = blockIdx.x * RPB;

  __shared__ __align__(16) char  xS[2][SLAB_BYTES];   // 16 KiB
  __shared__ __align__(16) float w1L[N_DIM];          // 8 KiB
  __shared__ __align__(16) float shL[N_DIM];          // 8 KiB
  __shared__ float pL[2][4][16];
  __shared__ float linL[2][2][16];

  // ---- staging addresses: LDS linear L = w*1024 + lane*16 ----
  // slab-row = L>>8, dst in-row byte = (lane&15)*16,
  // src in-row byte = dst ^ ((row&7)<<4)  (so swizzled reads see linear data)
  const int srow  = (w << 2) + (lane >> 4);                       // 0..31
  const int sbyte = ((lane & 15) << 4) ^ ((srow & 7) << 4);
  const float* xsrc = x + (size_t)(rowbase + srow) * N_DIM + (sbyte >> 2);
  char* ldst = &xS[0][0] + (w << 10);   // wave-uniform LDS base for this wave

  // ---- prologue: stage slab 0, prefetch vb(slab 0), stage w1/sh ----
  __builtin_amdgcn_global_load_lds((gas_t*)xsrc, (las_t*)ldst, 16, 0, 0);
  s16x8 pbv0 = *(const s16x8*)(vb + ((size_t)(0 + t) * 64 + lane) * 8);
  s16x8 pbv1 = *(const s16x8*)(vb + ((size_t)(4 + t) * 64 + lane) * 8);
  {
    const int t4 = tid << 2;            // 512 thr x 4 floats = 2048
    *(f32x4*)&w1L[t4] = *(const f32x4*)(w1 + t4);
    *(f32x4*)&shL[t4] = *(const f32x4*)(sh + t4);
  }
  __syncthreads();                      // drains slab-0 loads too

  f32x4 acc = {0.f, 0.f, 0.f, 0.f};
  float lin = 0.0f;

  const int rs     = (h << 4) + (lane & 15);   // slab row this lane reads
  const int rowoff = rs << 8;                  // rs*256
  const int swz    = (rs & 7) << 4;
  const int g8     = (lane >> 4) << 3;         // g*8 (floats)
  const int g32    = g8 << 2;                  // g*32 (bytes)

  for (int s = 0; s < NSLAB; ++s) {
    const int cur = s & 1;
    if (s + 1 < NSLAB)
      __builtin_amdgcn_global_load_lds((gas_t*)(xsrc + (s + 1) * SLABC),
                                       (las_t*)(ldst + (cur ^ 1) * SLAB_BYTES),
                                       16, 0, 0);
    s16x8 bv0 = pbv0, bv1 = pbv1;
    if (s + 1 < NSLAB) {
      const size_t ktn = (size_t)(s + 1) * 8;  // (2(s+1))*4
      pbv0 = *(const s16x8*)(vb + ((ktn + t) * 64 + lane) * 8);
      pbv1 = *(const s16x8*)(vb + ((ktn + 4 + t) * 64 + lane) * 8);
    }

    const char* xq = &xS[cur][0];
#pragma unroll
    for (int c = 0; c < 2; ++c) {
      const int A = (rowoff + (c << 7) + g32) ^ swz;
      f32x4 xa = *(const f32x4*)(xq + A);
      f32x4 xv = *(const f32x4*)(xq + (A ^ 16));
      bf16x8 Af;
#pragma unroll
      for (int i = 0; i < 4; ++i) {
        Af[i]     = (__bf16)xa[i];
        Af[4 + i] = (__bf16)xv[i];
      }
      if (t == c) {                      // lin for this chunk, waves t<2 only
        const int ki = s * 64 + c * 32 + g8;
        f32x4 wa = *(const f32x4*)(&w1L[ki]);
        f32x4 wb = *(const f32x4*)(&w1L[ki + 4]);
        f32x4 sa = *(const f32x4*)(&shL[ki]);
        f32x4 sb = *(const f32x4*)(&shL[ki + 4]);
#pragma unroll
        for (int i = 0; i < 4; ++i) {
          lin = fmaf(xa[i], wa[i] - xa[i] * sa[i], lin);
          lin = fmaf(xv[i], wb[i] - xv[i] * sb[i], lin);
        }
      }
      acc = __builtin_amdgcn_mfma_f32_16x16x32_bf16(
          Af, __builtin_bit_cast(bf16x8, c == 0 ? bv0 : bv1), acc, 0, 0, 0);
    }
    __syncthreads();
  }

  // ---- epilogue ----
  // C layout: F-col = 16t + (lane&15), row = 16h + 4*(lane>>4) + r
  float p[4];
#pragma unroll
  for (int r = 0; r < 4; ++r) {
    p[r] = acc[r] * acc[r];
    p[r] += __shfl_xor(p[r], 1);
    p[r] += __shfl_xor(p[r], 2);
    p[r] += __shfl_xor(p[r], 4);
    p[r] += __shfl_xor(p[r], 8);
  }
  if ((lane & 15) == 0) {
#pragma unroll
    for (int r = 0; r < 4; ++r)
      pL[h][t][((lane >> 4) << 2) + r] = p[r];
  }
  lin += __shfl_xor(lin, 16);
  lin += __shfl_xor(lin, 32);
  if (t < 2 && lane < 16) linL[h][t][lane] = lin;
  __syncthreads();

  if (w == 0 && lane < 32) {
    const int hh = lane >> 4, rr = lane & 15;
    float res = w0[0] + linL[hh][0][rr] + linL[hh][1][rr]
              + 0.5f * (pL[hh][0][rr] + pL[hh][1][rr] + pL[hh][2][rr] + pL[hh][3][rr]);
    out[rowbase + (hh << 4) + rr] = res;
  }
}

extern "C" void kernel_launch(void* const* d_in, const int* in_sizes, int n_in,
                              void* d_out, int out_size, void* d_ws, size_t ws_size,
                              hipStream_t stream) {
  const float* x  = (const float*)d_in[0];
  const float* w0 = (const float*)d_in[1];
  const float* w1 = (const float*)d_in[2];
  const float* v  = (const float*)d_in[3];
  float* out = (float*)d_out;

  unsigned short* vb = (unsigned short*)d_ws;           // 256 KiB
  float* sh = (float*)(vb + 131072);                    // 8 KiB

  fm_prep<<<72, 256, 0, stream>>>(v, vb, sh);
  fm_main<<<512, 512, 0, stream>>>(x, w0, w1, vb, sh, out);
}

// Round 6
// 45.135 us; speedup vs baseline: 1.0371x; 1.0371x over previous
//
#include <hip/hip_runtime.h>

#define N_DIM 2048
#define F_DIM 64

typedef __attribute__((ext_vector_type(4))) float  f32x4;
typedef __attribute__((ext_vector_type(8))) short  s16x8;
typedef __attribute__((ext_vector_type(8))) __bf16 bf16x8;

static __device__ __forceinline__ unsigned short f2bf(float f) {
  unsigned int u = __builtin_bit_cast(unsigned int, f);
  u += 0x7fffu + ((u >> 16) & 1u);      // RNE to bf16
  return (unsigned short)(u >> 16);
}

// Prep (grid 72):
//  blocks 0..63  — MFMA B-fragments of bf16(v): lane l holds
//    B[k = 8*(l/16)+j][col = l%16], stored [kt(64)][tile(4)][lane(64)][j(8)]
//  blocks 64..71 — s_half[k] = 0.5 * sum_f v[k][f]^2
__global__ __launch_bounds__(256) void fm_prep(const float* __restrict__ v,
                                               unsigned short* __restrict__ vb,
                                               float* __restrict__ sh) {
  const int blk = blockIdx.x;
  const int tid = threadIdx.x;
  if (blk < 64) {
    const int g  = blk * 256 + tid;
    const int fl = g & 63;
    const int t  = (g >> 6) & 3;
    const int kt = g >> 8;
    const int kbase = kt * 32 + ((fl >> 4) << 3);
    const int f = t * 16 + (fl & 15);
    s16x8 a;
#pragma unroll
    for (int j = 0; j < 8; ++j)
      a[j] = (short)f2bf(v[(size_t)(kbase + j) * F_DIM + f]);
    *(s16x8*)(vb + (size_t)g * 8) = a;
  } else {
    const int k = (blk - 64) * 256 + tid;
    const f32x4* row = (const f32x4*)(v + (size_t)k * F_DIM);
    float s = 0.0f;
#pragma unroll
    for (int i = 0; i < 16; ++i) {
      f32x4 q = row[i];
      s += q[0]*q[0] + q[1]*q[1] + q[2]*q[2] + q[3]*q[3];
    }
    sh[k] = 0.5f * s;
  }
}

// Main: 512 blocks x 512 threads (8 waves). Block owns 32 rows of x.
// Wave w owns K-eighth [w*256, w*256+256) and computes BOTH 16-row tiles
// for all 4 F-tiles from the SAME B-fragments (vb reuse 2x, 8 MFMA/iter).
// Register pipeline depth 2 on x (HBM) and vb (L2); no mid-loop barriers.
// lin = x.w1 - 0.5*x^2.s fused in fp32 (w1/sh from LDS).
// Epilogue: cross-wave K-sum via LDS tree, then out = w0 + lin + 0.5*sum_f xv^2.
__global__ __launch_bounds__(512, 4) void fm_main(const float* __restrict__ x,
                                                  const float* __restrict__ w0,
                                                  const float* __restrict__ w1,
                                                  const unsigned short* __restrict__ vb,
                                                  const float* __restrict__ sh,
                                                  float* __restrict__ out) {
  const int tid  = threadIdx.x;
  const int lane = tid & 63;
  const int w    = tid >> 6;            // 0..7
  const int rowbase = blockIdx.x * 32;
  const int g8   = ((lane >> 4) << 3);  // k-subchunk offset within 32: 0,8,16,24

  __shared__ __align__(16) float w1L[N_DIM];   // 8 KiB
  __shared__ __align__(16) float shL[N_DIM];   // 8 KiB
  __shared__ __align__(16) f32x4 accW[4][8][64]; // 32 KiB (epilogue tree)
  __shared__ float linL[8][2][16];             // 1 KiB

  const int kw = w * 256;               // this wave's K range (8 iters of 32)
  const float* xA = x + (size_t)(rowbase + (lane & 15)) * N_DIM + kw + g8;
  const float* xB = xA + 16 * N_DIM;
  const unsigned short* vbase = vb + ((size_t)w * 2048 + lane) * 8;

  // ---- prologue: prefetch slot 0 ----
  f32x4 pxa[2], pxb[2], pxc[2], pxd[2];
  s16x8 pb[2][4];
  pxa[0] = *(const f32x4*)(xA);
  pxb[0] = *(const f32x4*)(xA + 4);
  pxc[0] = *(const f32x4*)(xB);
  pxd[0] = *(const f32x4*)(xB + 4);
#pragma unroll
  for (int t = 0; t < 4; ++t)
    pb[0][t] = *(const s16x8*)(vbase + t * 512);

  // ---- stage w1/sh into LDS (512 thr x 4 floats each) ----
  {
    const int t4 = tid << 2;
    *(f32x4*)&w1L[t4] = *(const f32x4*)(w1 + t4);
    *(f32x4*)&shL[t4] = *(const f32x4*)(sh + t4);
  }
  __syncthreads();

  f32x4 acc[2][4] = {};
  float linA = 0.0f, linB = 0.0f;

#pragma unroll
  for (int s = 0; s < 8; ++s) {
    const int cur = s & 1, nxt = cur ^ 1;
    if (s < 7) {                        // next iteration's 8 vmem loads
      const int kc = (s + 1) * 32;
      pxa[nxt] = *(const f32x4*)(xA + kc);
      pxb[nxt] = *(const f32x4*)(xA + kc + 4);
      pxc[nxt] = *(const f32x4*)(xB + kc);
      pxd[nxt] = *(const f32x4*)(xB + kc + 4);
      const unsigned short* vbp = vbase + (s + 1) * 2048;
#pragma unroll
      for (int t = 0; t < 4; ++t)
        pb[nxt][t] = *(const s16x8*)(vbp + t * 512);
    }
    const int ki = kw + s * 32 + g8;
    f32x4 xa = pxa[cur], xb = pxb[cur], xc = pxc[cur], xd = pxd[cur];
    {
      f32x4 wa = *(const f32x4*)(&w1L[ki]);
      f32x4 wbv = *(const f32x4*)(&w1L[ki + 4]);
      f32x4 sa = *(const f32x4*)(&shL[ki]);
      f32x4 sb = *(const f32x4*)(&shL[ki + 4]);
#pragma unroll
      for (int i = 0; i < 4; ++i) {
        linA = fmaf(xa[i], wa[i]  - xa[i] * sa[i], linA);
        linA = fmaf(xb[i], wbv[i] - xb[i] * sb[i], linA);
        linB = fmaf(xc[i], wa[i]  - xc[i] * sa[i], linB);
        linB = fmaf(xd[i], wbv[i] - xd[i] * sb[i], linB);
      }
    }
    bf16x8 Alo, Ahi;
#pragma unroll
    for (int i = 0; i < 4; ++i) {
      Alo[i]     = (__bf16)xa[i];
      Alo[4 + i] = (__bf16)xb[i];
      Ahi[i]     = (__bf16)xc[i];
      Ahi[4 + i] = (__bf16)xd[i];
    }
#pragma unroll
    for (int t = 0; t < 4; ++t) {
      bf16x8 Bv = __builtin_bit_cast(bf16x8, pb[cur][t]);
      acc[0][t] = __builtin_amdgcn_mfma_f32_16x16x32_bf16(Alo, Bv, acc[0][t], 0, 0, 0);
      acc[1][t] = __builtin_amdgcn_mfma_f32_16x16x32_bf16(Ahi, Bv, acc[1][t], 0, 0, 0);
    }
  }

  // ---- lin reduce: lanes {r,r+16,r+32,r+48} hold partials of row r ----
  linA += __shfl_xor(linA, 16);
  linA += __shfl_xor(linA, 32);
  linB += __shfl_xor(linB, 16);
  linB += __shfl_xor(linB, 32);
  if (lane < 16) {
    linL[w][0][lane] = linA;
    linL[w][1][lane] = linB;
  }

  // ---- cross-wave K-sum of acc (tree: 8 -> 4 -> 1) ----
  if (w >= 4) {
#pragma unroll
    for (int h = 0; h < 2; ++h)
#pragma unroll
      for (int t = 0; t < 4; ++t)
        accW[w - 4][h * 4 + t][lane] = acc[h][t];
  }
  __syncthreads();
  if (w < 4) {
#pragma unroll
    for (int h = 0; h < 2; ++h)
#pragma unroll
      for (int t = 0; t < 4; ++t)
        acc[h][t] += accW[w][h * 4 + t][lane];
  }
  __syncthreads();
  if (w >= 1 && w < 4) {
#pragma unroll
    for (int h = 0; h < 2; ++h)
#pragma unroll
      for (int t = 0; t < 4; ++t)
        accW[w - 1][h * 4 + t][lane] = acc[h][t];
  }
  __syncthreads();

  if (w == 0) {
#pragma unroll
    for (int ww = 0; ww < 3; ++ww)
#pragma unroll
      for (int h = 0; h < 2; ++h)
#pragma unroll
        for (int t = 0; t < 4; ++t)
          acc[h][t] += accW[ww][h * 4 + t][lane];

    // C layout: col = lane&15 (within F-tile t), row = 4*(lane>>4) + r
    float p[2][4];
#pragma unroll
    for (int h = 0; h < 2; ++h)
#pragma unroll
      for (int r = 0; r < 4; ++r) {
        float q = 0.0f;
#pragma unroll
        for (int t = 0; t < 4; ++t)
          q += acc[h][t][r] * acc[h][t][r];
        q += __shfl_xor(q, 1);
        q += __shfl_xor(q, 2);
        q += __shfl_xor(q, 4);
        q += __shfl_xor(q, 8);
        p[h][r] = q;
      }
    if ((lane & 15) == 0) {
      const int g = lane >> 4;
      const float w0v = w0[0];
#pragma unroll
      for (int h = 0; h < 2; ++h)
#pragma unroll
        for (int r = 0; r < 4; ++r) {
          const int row = g * 4 + r;
          float lt = 0.0f;
#pragma unroll
          for (int ww = 0; ww < 8; ++ww)
            lt += linL[ww][h][row];
          out[rowbase + h * 16 + row] = w0v + lt + 0.5f * p[h][r];
        }
    }
  }
}

extern "C" void kernel_launch(void* const* d_in, const int* in_sizes, int n_in,
                              void* d_out, int out_size, void* d_ws, size_t ws_size,
                              hipStream_t stream) {
  const float* x  = (const float*)d_in[0];
  const float* w0 = (const float*)d_in[1];
  const float* w1 = (const float*)d_in[2];
  const float* v  = (const float*)d_in[3];
  float* out = (float*)d_out;

  unsigned short* vb = (unsigned short*)d_ws;           // 256 KiB
  float* sh = (float*)(vb + 131072);                    // 8 KiB

  fm_prep<<<72, 256, 0, stream>>>(v, vb, sh);
  fm_main<<<512, 512, 0, stream>>>(x, w0, w1, vb, sh, out);
}

// Round 7
// 32.649 us; speedup vs baseline: 1.4336x; 1.3824x over previous
//
#include <hip/hip_runtime.h>

#define N_DIM 2048
#define F_DIM 64

typedef __attribute__((ext_vector_type(4))) float  f32x4;
typedef __attribute__((ext_vector_type(8))) short  s16x8;
typedef __attribute__((ext_vector_type(8))) __bf16 bf16x8;

static __device__ __forceinline__ unsigned short f2bf(float f) {
  unsigned int u = __builtin_bit_cast(unsigned int, f);
  u += 0x7fffu + ((u >> 16) & 1u);      // RNE to bf16
  return (unsigned short)(u >> 16);
}

// Prep (grid 72):
//  blocks 0..63  — MFMA B-fragments of bf16(v): lane l holds
//    B[k = 8*(l/16)+j][col = l%16], stored [kt(64)][tile(4)][lane(64)][j(8)]
//  blocks 64..71 — s_half[k] = 0.5 * sum_f v[k][f]^2
__global__ __launch_bounds__(256) void fm_prep(const float* __restrict__ v,
                                               unsigned short* __restrict__ vb,
                                               float* __restrict__ sh) {
  const int blk = blockIdx.x;
  const int tid = threadIdx.x;
  if (blk < 64) {
    const int g  = blk * 256 + tid;
    const int fl = g & 63;
    const int t  = (g >> 6) & 3;
    const int kt = g >> 8;
    const int kbase = kt * 32 + ((fl >> 4) << 3);
    const int f = t * 16 + (fl & 15);
    s16x8 a;
#pragma unroll
    for (int j = 0; j < 8; ++j)
      a[j] = (short)f2bf(v[(size_t)(kbase + j) * F_DIM + f]);
    *(s16x8*)(vb + (size_t)g * 8) = a;
  } else {
    const int k = (blk - 64) * 256 + tid;
    const f32x4* row = (const f32x4*)(v + (size_t)k * F_DIM);
    float s = 0.0f;
#pragma unroll
    for (int i = 0; i < 16; ++i) {
      f32x4 q = row[i];
      s += q[0]*q[0] + q[1]*q[1] + q[2]*q[2] + q[3]*q[3];
    }
    sh[k] = 0.5f * s;
  }
}

// Main: 512 blocks x 256 threads (4 waves). Block owns 32 rows of x.
// Wave w owns K-quarter [w*512, w*512+512), 16 iters of 32-k, and computes
// BOTH 16-row tiles for all 4 F-tiles from the SAME 4 B-fragments
// (vb reuse 2x; 8 MFMA/iter). Register pipeline: vb depth 1 issued FIRST,
// x depth 2 issued second (FIFO: vb-wait must not drain young x loads).
// 2 blocks/CU -> 2 waves/SIMD; launch_bounds(256,2) => 256-VGPR budget.
// lin = x.w1 - 0.5*x^2.s fused in fp32 (w1/sh from LDS).
__global__ __launch_bounds__(256, 2) void fm_main(const float* __restrict__ x,
                                                  const float* __restrict__ w0,
                                                  const float* __restrict__ w1,
                                                  const unsigned short* __restrict__ vb,
                                                  const float* __restrict__ sh,
                                                  float* __restrict__ out) {
  const int tid  = threadIdx.x;
  const int lane = tid & 63;
  const int w    = tid >> 6;            // 0..3
  const int rowbase = blockIdx.x * 32;
  const int g8   = ((lane >> 4) << 3);  // k-subchunk offset within 32: 0,8,16,24

  __shared__ __align__(16) float w1L[N_DIM];     // 8 KiB
  __shared__ __align__(16) float shL[N_DIM];     // 8 KiB
  __shared__ __align__(16) f32x4 accW[3][8][64]; // 24 KiB (epilogue)
  __shared__ float linL[4][2][16];               // 512 B

  const int kw = w * 512;               // this wave's K range (16 iters of 32)
  const float* xA = x + (size_t)(rowbase + (lane & 15)) * N_DIM + kw + g8;
  const float* xB = xA + 16 * N_DIM;
  const unsigned short* vbase = vb + ((size_t)w * 4096 + lane) * 8;

  // ---- prologue: vb slot 0; x slots 0,1 ----
  s16x8 pb[2][4];
  f32x4 pxa[3], pxb[3], pxc[3], pxd[3];
#pragma unroll
  for (int t = 0; t < 4; ++t)
    pb[0][t] = *(const s16x8*)(vbase + t * 512);
#pragma unroll
  for (int s = 0; s < 2; ++s) {
    const int kc = s * 32;
    pxa[s] = *(const f32x4*)(xA + kc);
    pxb[s] = *(const f32x4*)(xA + kc + 4);
    pxc[s] = *(const f32x4*)(xB + kc);
    pxd[s] = *(const f32x4*)(xB + kc + 4);
  }

  // ---- stage w1/sh into LDS (256 thr x 8 floats each) ----
  {
    const int t8 = tid << 3;
    *(f32x4*)&w1L[t8]     = *(const f32x4*)(w1 + t8);
    *(f32x4*)&w1L[t8 + 4] = *(const f32x4*)(w1 + t8 + 4);
    *(f32x4*)&shL[t8]     = *(const f32x4*)(sh + t8);
    *(f32x4*)&shL[t8 + 4] = *(const f32x4*)(sh + t8 + 4);
  }
  __syncthreads();

  f32x4 acc[2][4] = {};
  float linA = 0.0f, linB = 0.0f;

#pragma unroll
  for (int s = 0; s < 16; ++s) {
    // vb prefetch FIRST (depth 1, L2-resident)
    if (s < 15) {
      const unsigned short* vbp = vbase + (size_t)(s + 1) * 2048;
#pragma unroll
      for (int t = 0; t < 4; ++t)
        pb[(s + 1) & 1][t] = *(const s16x8*)(vbp + t * 512);
    }
    // x prefetch SECOND (depth 2, HBM): issue slot s+2
    if (s < 14) {
      const int kc = (s + 2) * 32;
      const int sl = (s + 2) % 3;
      pxa[sl] = *(const f32x4*)(xA + kc);
      pxb[sl] = *(const f32x4*)(xA + kc + 4);
      pxc[sl] = *(const f32x4*)(xB + kc);
      pxd[sl] = *(const f32x4*)(xB + kc + 4);
    }
    const int xs = s % 3;
    const int ki = kw + s * 32 + g8;
    f32x4 xa = pxa[xs], xb = pxb[xs], xc = pxc[xs], xd = pxd[xs];
    {
      f32x4 wa  = *(const f32x4*)(&w1L[ki]);
      f32x4 wb2 = *(const f32x4*)(&w1L[ki + 4]);
      f32x4 sa  = *(const f32x4*)(&shL[ki]);
      f32x4 sb2 = *(const f32x4*)(&shL[ki + 4]);
#pragma unroll
      for (int i = 0; i < 4; ++i) {
        linA = fmaf(xa[i], wa[i]  - xa[i] * sa[i],  linA);
        linA = fmaf(xb[i], wb2[i] - xb[i] * sb2[i], linA);
        linB = fmaf(xc[i], wa[i]  - xc[i] * sa[i],  linB);
        linB = fmaf(xd[i], wb2[i] - xd[i] * sb2[i], linB);
      }
    }
    bf16x8 Alo, Ahi;
#pragma unroll
    for (int i = 0; i < 4; ++i) {
      Alo[i]     = (__bf16)xa[i];
      Alo[4 + i] = (__bf16)xb[i];
      Ahi[i]     = (__bf16)xc[i];
      Ahi[4 + i] = (__bf16)xd[i];
    }
#pragma unroll
    for (int t = 0; t < 4; ++t) {
      bf16x8 Bv = __builtin_bit_cast(bf16x8, pb[s & 1][t]);
      acc[0][t] = __builtin_amdgcn_mfma_f32_16x16x32_bf16(Alo, Bv, acc[0][t], 0, 0, 0);
      acc[1][t] = __builtin_amdgcn_mfma_f32_16x16x32_bf16(Ahi, Bv, acc[1][t], 0, 0, 0);
    }
  }

  // ---- lin reduce: lanes {r,r+16,r+32,r+48} hold partials of row r ----
  linA += __shfl_xor(linA, 16);
  linA += __shfl_xor(linA, 32);
  linB += __shfl_xor(linB, 16);
  linB += __shfl_xor(linB, 32);
  if (lane < 16) {
    linL[w][0][lane] = linA;
    linL[w][1][lane] = linB;
  }

  // ---- cross-wave K-sum: waves 1..3 dump, wave 0 reduces ----
  if (w > 0) {
#pragma unroll
    for (int h = 0; h < 2; ++h)
#pragma unroll
      for (int t = 0; t < 4; ++t)
        accW[w - 1][h * 4 + t][lane] = acc[h][t];
  }
  __syncthreads();

  if (w == 0) {
#pragma unroll
    for (int ww = 0; ww < 3; ++ww)
#pragma unroll
      for (int h = 0; h < 2; ++h)
#pragma unroll
        for (int t = 0; t < 4; ++t)
          acc[h][t] += accW[ww][h * 4 + t][lane];

    // C layout: col = lane&15 (within F-tile t), row = 4*(lane>>4) + r
    float p[2][4];
#pragma unroll
    for (int h = 0; h < 2; ++h)
#pragma unroll
      for (int r = 0; r < 4; ++r) {
        float q = 0.0f;
#pragma unroll
        for (int t = 0; t < 4; ++t)
          q += acc[h][t][r] * acc[h][t][r];
        q += __shfl_xor(q, 1);
        q += __shfl_xor(q, 2);
        q += __shfl_xor(q, 4);
        q += __shfl_xor(q, 8);
        p[h][r] = q;
      }
    if ((lane & 15) == 0) {
      const int g = lane >> 4;
      const float w0v = w0[0];
#pragma unroll
      for (int h = 0; h < 2; ++h)
#pragma unroll
        for (int r = 0; r < 4; ++r) {
          const int row = g * 4 + r;
          float lt = linL[0][h][row] + linL[1][h][row]
                   + linL[2][h][row] + linL[3][h][row];
          out[rowbase + h * 16 + row] = w0v + lt + 0.5f * p[h][r];
        }
    }
  }
}

extern "C" void kernel_launch(void* const* d_in, const int* in_sizes, int n_in,
                              void* d_out, int out_size, void* d_ws, size_t ws_size,
                              hipStream_t stream) {
  const float* x  = (const float*)d_in[0];
  const float* w0 = (const float*)d_in[1];
  const float* w1 = (const float*)d_in[2];
  const float* v  = (const float*)d_in[3];
  float* out = (float*)d_out;

  unsigned short* vb = (unsigned short*)d_ws;           // 256 KiB
  float* sh = (float*)(vb + 131072);                    // 8 KiB

  fm_prep<<<72, 256, 0, stream>>>(v, vb, sh);
  fm_main<<<512, 256, 0, stream>>>(x, w0, w1, vb, sh, out);
}